// Round 1
// baseline (1710.045 us; speedup 1.0000x reference)
//
#include <hip/hip_runtime.h>

// UIR_KG: x -> [spmm side=A@x] -> sum_emb=LReLU((x+side)W1^T+b1),
//                bi_emb=LReLU((x*side)W2^T+b2), x'=sum+bi, out=normalize(x')
// Output [N, 112] = concat(E, norm(x1), norm(x2)), row stride 112.

static __device__ __forceinline__ float leaky(float v) {
    return v > 0.0f ? v : 0.01f * v;
}

// Copy E into out[:, 0:64]. One thread per (node, 4-dim group).
__global__ void copy_E_kernel(const float* __restrict__ E, float* __restrict__ out, int N) {
    int tid = blockIdx.x * blockDim.x + threadIdx.x;
    int total = N * 16;
    if (tid >= total) return;
    int i = tid >> 4, g = tid & 15;
    float4 v = reinterpret_cast<const float4*>(E)[(size_t)i * 16 + g];
    *reinterpret_cast<float4*>(out + (size_t)i * 112 + g * 4) = v;
}

// side[rows[e]][d] += ev[e] * x[cols[e]][d]; thread = (edge, dim) pair.
// 2^LOGD consecutive threads share one edge -> index loads broadcast,
// gather/scatter contiguous per edge.
template<int LOGD>
__global__ void spmm_kernel(const float* __restrict__ x, const float* __restrict__ ev,
                            const int* __restrict__ rows, const int* __restrict__ cols,
                            float* __restrict__ side, int total) {
    int t = blockIdx.x * blockDim.x + threadIdx.x;
    if (t >= total) return;
    int e = t >> LOGD;
    int d = t & ((1 << LOGD) - 1);
    int r = rows[e], c = cols[e];
    float v = ev[e] * x[((size_t)c << LOGD) + d];
    unsafeAtomicAdd(side + (((size_t)r << LOGD) + d), v);  // native global_atomic_add_f32
}

// One thread per node: h1 = x+side, h2 = x*side, two small dense layers from
// LDS-transposed W (uniform-address broadcast reads), leaky, sum, L2-normalize.
template<int DIN, int DOUT>
__global__ void layer_kernel(const float* __restrict__ x, const float* __restrict__ side,
                             const float* __restrict__ W1, const float* __restrict__ b1,
                             const float* __restrict__ W2, const float* __restrict__ b2,
                             float* __restrict__ xnext,  // may be null (last layer)
                             float* __restrict__ out, int out_col0, int N) {
    __shared__ __align__(16) float sW1[DIN * DOUT + DOUT];  // transposed [k][j], + bias tail
    __shared__ __align__(16) float sW2[DIN * DOUT + DOUT];
    for (int idx = threadIdx.x; idx < DIN * DOUT; idx += blockDim.x) {
        int j = idx / DIN, k = idx % DIN;
        sW1[k * DOUT + j] = W1[idx];
        sW2[k * DOUT + j] = W2[idx];
    }
    if (threadIdx.x < DOUT) {
        sW1[DIN * DOUT + threadIdx.x] = b1[threadIdx.x];
        sW2[DIN * DOUT + threadIdx.x] = b2[threadIdx.x];
    }
    __syncthreads();

    int i = blockIdx.x * blockDim.x + threadIdx.x;
    if (i >= N) return;

    float acc1[DOUT], acc2[DOUT];
#pragma unroll
    for (int j = 0; j < DOUT; j++) {
        acc1[j] = sW1[DIN * DOUT + j];
        acc2[j] = sW2[DIN * DOUT + j];
    }

    const float4* xp = reinterpret_cast<const float4*>(x + (size_t)i * DIN);
    const float4* sp = reinterpret_cast<const float4*>(side + (size_t)i * DIN);
    for (int k4 = 0; k4 < DIN / 4; k4++) {
        float4 a = xp[k4];
        float4 s = sp[k4];
        float h1[4] = {a.x + s.x, a.y + s.y, a.z + s.z, a.w + s.w};
        float h2[4] = {a.x * s.x, a.y * s.y, a.z * s.z, a.w * s.w};
#pragma unroll
        for (int u = 0; u < 4; u++) {
            int k = k4 * 4 + u;
            const float4* w1p = reinterpret_cast<const float4*>(&sW1[k * DOUT]);
            const float4* w2p = reinterpret_cast<const float4*>(&sW2[k * DOUT]);
#pragma unroll
            for (int j4 = 0; j4 < DOUT / 4; j4++) {
                float4 w1 = w1p[j4];
                float4 w2 = w2p[j4];
                acc1[j4 * 4 + 0] += h1[u] * w1.x;
                acc1[j4 * 4 + 1] += h1[u] * w1.y;
                acc1[j4 * 4 + 2] += h1[u] * w1.z;
                acc1[j4 * 4 + 3] += h1[u] * w1.w;
                acc2[j4 * 4 + 0] += h2[u] * w2.x;
                acc2[j4 * 4 + 1] += h2[u] * w2.y;
                acc2[j4 * 4 + 2] += h2[u] * w2.z;
                acc2[j4 * 4 + 3] += h2[u] * w2.w;
            }
        }
    }

    float y[DOUT];
    float nrm = 0.0f;
#pragma unroll
    for (int j = 0; j < DOUT; j++) {
        float v = leaky(acc1[j]) + leaky(acc2[j]);
        y[j] = v;
        nrm += v * v;
    }
    float inv = 1.0f / fmaxf(sqrtf(nrm), 1e-12f);

    float* o = out + (size_t)i * 112 + out_col0;
#pragma unroll
    for (int j = 0; j < DOUT; j++) {
        if (xnext) xnext[(size_t)i * DOUT + j] = y[j];
        o[j] = y[j] * inv;
    }
}

extern "C" void kernel_launch(void* const* d_in, const int* in_sizes, int n_in,
                              void* d_out, int out_size, void* d_ws, size_t ws_size,
                              hipStream_t stream) {
    const float* E    = (const float*)d_in[0];
    const float* ev   = (const float*)d_in[1];
    const int*   rows = (const int*)d_in[2];
    const int*   cols = (const int*)d_in[3];
    const float* W1_0 = (const float*)d_in[4];
    const float* b1_0 = (const float*)d_in[5];
    const float* W2_0 = (const float*)d_in[6];
    const float* b2_0 = (const float*)d_in[7];
    const float* W1_1 = (const float*)d_in[8];
    const float* b1_1 = (const float*)d_in[9];
    const float* W2_1 = (const float*)d_in[10];
    const float* b2_1 = (const float*)d_in[11];
    float* out = (float*)d_out;

    int N = in_sizes[0] / 64;
    int n_edges = in_sizes[1];

    // ws layout: side0 [N*64] | side1 [N*32] | x1 [N*32]
    float* side0 = (float*)d_ws;
    float* side1 = side0 + (size_t)N * 64;
    float* x1    = side1 + (size_t)N * 32;

    // zero the two accumulators (side0+side1 contiguous)
    hipMemsetAsync(d_ws, 0, (size_t)N * 96 * sizeof(float), stream);

    copy_E_kernel<<<(N * 16 + 255) / 256, 256, 0, stream>>>(E, out, N);

    int total0 = n_edges * 64;
    spmm_kernel<6><<<(total0 + 255) / 256, 256, 0, stream>>>(E, ev, rows, cols, side0, total0);

    layer_kernel<64, 32><<<(N + 255) / 256, 256, 0, stream>>>(
        E, side0, W1_0, b1_0, W2_0, b2_0, x1, out, 64, N);

    int total1 = n_edges * 32;
    spmm_kernel<5><<<(total1 + 255) / 256, 256, 0, stream>>>(x1, ev, rows, cols, side1, total1);

    layer_kernel<32, 16><<<(N + 255) / 256, 256, 0, stream>>>(
        x1, side1, W1_1, b1_1, W2_1, b2_1, nullptr, out, 96, N);
}

// Round 3
// 960.971 us; speedup vs baseline: 1.7795x; 1.7795x over previous
//
#include <hip/hip_runtime.h>

// UIR_KG — CSR-build + pull-based SpMM fused with the KGAT bi-interaction layer.
//
// Round-1 evidence: push-spmm f32 atomics write through to HBM (WRITE_SIZE ==
// edges*256B exactly) at ~2 TB/s effective -> 1033+517 us. This version builds
// CSR per call (hist + scan + scatter, int atomics only), then each row PULLS
// its neighbors (gathers are L3-resident, no atomic traffic), and the dense
// layer + L2-normalize are fused into the pull kernel (no side[] arrays).
//
// ws layout: pairs[(col,val) int2 * E] | cursor[N] | blk[1K ints] | x1[N*32]
//            = 38.4MB + 0.6MB + 4KB + 19.2MB ~= 58.2MB.

static __device__ __forceinline__ float leaky(float v) {
    return v > 0.0f ? v : 0.01f * v;
}

// ---------------- output col 0..63 = E verbatim ----------------
__global__ void copy_E_kernel(const float* __restrict__ E, float* __restrict__ out, int N) {
    int tid = blockIdx.x * blockDim.x + threadIdx.x;
    int total = N * 16;
    if (tid >= total) return;
    int i = tid >> 4, g = tid & 15;
    float4 v = reinterpret_cast<const float4*>(E)[(size_t)i * 16 + g];
    *reinterpret_cast<float4*>(out + (size_t)i * 112 + g * 4) = v;
}

// ---------------- CSR build ----------------
__global__ void hist_kernel(const int* __restrict__ rows, int* __restrict__ cnt, int NE) {
    int e = blockIdx.x * blockDim.x + threadIdx.x;
    if (e < NE) atomicAdd(&cnt[rows[e]], 1);
}

// per-1024-chunk exclusive scan in place; chunk totals to blk[]
__global__ void scan1_kernel(int* __restrict__ cur, int* __restrict__ blk, int N) {
    __shared__ int s[1024];
    int i = blockIdx.x * 1024 + threadIdx.x;
    int v = (i < N) ? cur[i] : 0;
    s[threadIdx.x] = v;
    __syncthreads();
    for (int off = 1; off < 1024; off <<= 1) {
        int t = (threadIdx.x >= (unsigned)off) ? s[threadIdx.x - off] : 0;
        __syncthreads();
        s[threadIdx.x] += t;
        __syncthreads();
    }
    if (i < N) cur[i] = s[threadIdx.x] - v;  // exclusive
    if (threadIdx.x == 1023) blk[blockIdx.x] = s[1023];
}

// single-block exclusive scan of the (<=256) chunk totals
__global__ void scan2_kernel(int* __restrict__ blk, int nb) {
    __shared__ int s[256];
    int v = (threadIdx.x < (unsigned)nb) ? blk[threadIdx.x] : 0;
    s[threadIdx.x] = v;
    __syncthreads();
    for (int off = 1; off < 256; off <<= 1) {
        int t = (threadIdx.x >= (unsigned)off) ? s[threadIdx.x - off] : 0;
        __syncthreads();
        s[threadIdx.x] += t;
        __syncthreads();
    }
    if (threadIdx.x < (unsigned)nb) blk[threadIdx.x] = s[threadIdx.x] - v;
}

__global__ void scan3_kernel(int* __restrict__ cur, const int* __restrict__ blk, int N) {
    int i = blockIdx.x * 1024 + threadIdx.x;  // blockDim == 1024
    if (i < N) cur[i] += blk[blockIdx.x];
}

// scatter edges into row-grouped pairs; cursor[r] ends at inclusive end[r]
__global__ void scatter_kernel(const int* __restrict__ rows, const int* __restrict__ cols,
                               const float* __restrict__ ev, int* __restrict__ cur,
                               int2* __restrict__ pairs, int NE) {
    int e = blockIdx.x * blockDim.x + threadIdx.x;
    if (e >= NE) return;
    int pos = atomicAdd(&cur[rows[e]], 1);
    pairs[pos] = make_int2(cols[e], __float_as_int(ev[e]));
}

// ---------------- fused pull-spmm + bi-interaction layer ----------------
// Q = DIN/4 threads per row (float4 per thread), RPB = 256/Q rows per block.
// side accumulated in registers; h1/h2 staged in padded LDS; W1/W2 in padded
// LDS (float4 reads, 2-way-max bank aliasing = free); each thread then owns
// output dims {q, q+Q}; row L2-norm via shfl_xor over the Q-lane group.
template<int DIN, int DOUT>
__global__ __launch_bounds__(256) void pull_layer_kernel(
    const float* __restrict__ x, const int2* __restrict__ pairs,
    const int* __restrict__ cursor,
    const float* __restrict__ W1, const float* __restrict__ b1,
    const float* __restrict__ W2, const float* __restrict__ b2,
    float* __restrict__ xnext,  // unnormalized x' (null on last layer)
    float* __restrict__ out, int out_col0, int N) {
    constexpr int Q   = DIN / 4;
    constexpr int RPB = 256 / Q;
    constexpr int LD  = DIN + 4;   // padded stride in floats (16B-aligned rows)
    constexpr int LD4 = LD / 4;
    static_assert(DOUT == 2 * Q, "thread owns exactly 2 output dims");

    __shared__ float sW1[DOUT * LD];
    __shared__ float sW2[DOUT * LD];
    __shared__ float hb[2][RPB][LD];

    for (int idx = threadIdx.x; idx < DOUT * DIN; idx += 256) {
        int j = idx / DIN, k = idx % DIN;
        sW1[j * LD + k] = W1[idx];
        sW2[j * LD + k] = W2[idx];
    }

    int lr  = threadIdx.x / Q;
    int q   = threadIdx.x % Q;
    int row = blockIdx.x * RPB + lr;

    if (row < N) {
        int start = row ? cursor[row - 1] : 0;
        int end   = cursor[row];
        const float4* xv = reinterpret_cast<const float4*>(x);
        float4 acc = make_float4(0.f, 0.f, 0.f, 0.f);
        int e = start;
        for (; e + 1 < end; e += 2) {  // 2 gathers in flight
            int2 p0 = pairs[e];
            int2 p1 = pairs[e + 1];
            float4 g0 = xv[(size_t)p0.x * Q + q];
            float4 g1 = xv[(size_t)p1.x * Q + q];
            float v0 = __int_as_float(p0.y), v1 = __int_as_float(p1.y);
            acc.x += v0 * g0.x; acc.y += v0 * g0.y; acc.z += v0 * g0.z; acc.w += v0 * g0.w;
            acc.x += v1 * g1.x; acc.y += v1 * g1.y; acc.z += v1 * g1.z; acc.w += v1 * g1.w;
        }
        if (e < end) {
            int2 p0 = pairs[e];
            float4 g0 = xv[(size_t)p0.x * Q + q];
            float v0 = __int_as_float(p0.y);
            acc.x += v0 * g0.x; acc.y += v0 * g0.y; acc.z += v0 * g0.z; acc.w += v0 * g0.w;
        }
        float4 xr = xv[(size_t)row * Q + q];
        float4 h1 = make_float4(xr.x + acc.x, xr.y + acc.y, xr.z + acc.z, xr.w + acc.w);
        float4 h2 = make_float4(xr.x * acc.x, xr.y * acc.y, xr.z * acc.z, xr.w * acc.w);
        *reinterpret_cast<float4*>(&hb[0][lr][q * 4]) = h1;
        *reinterpret_cast<float4*>(&hb[1][lr][q * 4]) = h2;
    }
    __syncthreads();
    if (row >= N) return;

    float a0 = b1[q], a1 = b1[q + Q], a2 = b2[q], a3 = b2[q + Q];
    const float4* w1v = reinterpret_cast<const float4*>(sW1);
    const float4* w2v = reinterpret_cast<const float4*>(sW2);
    const float4* h1v = reinterpret_cast<const float4*>(&hb[0][lr][0]);
    const float4* h2v = reinterpret_cast<const float4*>(&hb[1][lr][0]);
#pragma unroll
    for (int k4 = 0; k4 < DIN / 4; k4++) {
        float4 h1 = h1v[k4];
        float4 h2 = h2v[k4];
        float4 wa = w1v[q * LD4 + k4];
        float4 wb = w1v[(q + Q) * LD4 + k4];
        float4 wc = w2v[q * LD4 + k4];
        float4 wd = w2v[(q + Q) * LD4 + k4];
        a0 += h1.x * wa.x + h1.y * wa.y + h1.z * wa.z + h1.w * wa.w;
        a1 += h1.x * wb.x + h1.y * wb.y + h1.z * wb.z + h1.w * wb.w;
        a2 += h2.x * wc.x + h2.y * wc.y + h2.z * wc.z + h2.w * wc.w;
        a3 += h2.x * wd.x + h2.y * wd.y + h2.z * wd.z + h2.w * wd.w;
    }
    float y0 = leaky(a0) + leaky(a2);
    float y1 = leaky(a1) + leaky(a3);
    float nrm = y0 * y0 + y1 * y1;
#pragma unroll
    for (int m = 1; m < Q; m <<= 1) nrm += __shfl_xor(nrm, m, 64);
    float inv = 1.0f / fmaxf(sqrtf(nrm), 1e-12f);
    if (xnext) {
        xnext[(size_t)row * DOUT + q]     = y0;
        xnext[(size_t)row * DOUT + q + Q] = y1;
    }
    float* o = out + (size_t)row * 112 + out_col0;
    o[q]     = y0 * inv;
    o[q + Q] = y1 * inv;
}

// ---------------- round-1 fallback (tiny ws) ----------------
template<int LOGD>
__global__ void spmm_kernel(const float* __restrict__ x, const float* __restrict__ ev,
                            const int* __restrict__ rows, const int* __restrict__ cols,
                            float* __restrict__ side, int total) {
    int t = blockIdx.x * blockDim.x + threadIdx.x;
    if (t >= total) return;
    int e = t >> LOGD;
    int d = t & ((1 << LOGD) - 1);
    float v = ev[e] * x[((size_t)cols[e] << LOGD) + d];
    unsafeAtomicAdd(side + (((size_t)rows[e] << LOGD) + d), v);
}

template<int DIN, int DOUT>
__global__ void layer_kernel(const float* __restrict__ x, const float* __restrict__ side,
                             const float* __restrict__ W1, const float* __restrict__ b1,
                             const float* __restrict__ W2, const float* __restrict__ b2,
                             float* __restrict__ xnext, float* __restrict__ out,
                             int out_col0, int N) {
    __shared__ float sW1[DIN * DOUT + DOUT];
    __shared__ float sW2[DIN * DOUT + DOUT];
    for (int idx = threadIdx.x; idx < DIN * DOUT; idx += blockDim.x) {
        int j = idx / DIN, k = idx % DIN;
        sW1[k * DOUT + j] = W1[idx];
        sW2[k * DOUT + j] = W2[idx];
    }
    if (threadIdx.x < DOUT) {
        sW1[DIN * DOUT + threadIdx.x] = b1[threadIdx.x];
        sW2[DIN * DOUT + threadIdx.x] = b2[threadIdx.x];
    }
    __syncthreads();
    int i = blockIdx.x * blockDim.x + threadIdx.x;
    if (i >= N) return;
    float acc1[DOUT], acc2[DOUT];
#pragma unroll
    for (int j = 0; j < DOUT; j++) {
        acc1[j] = sW1[DIN * DOUT + j];
        acc2[j] = sW2[DIN * DOUT + j];
    }
    const float4* xp = reinterpret_cast<const float4*>(x + (size_t)i * DIN);
    const float4* sp = reinterpret_cast<const float4*>(side + (size_t)i * DIN);
    for (int k4 = 0; k4 < DIN / 4; k4++) {
        float4 a = xp[k4], s = sp[k4];
        float h1[4] = {a.x + s.x, a.y + s.y, a.z + s.z, a.w + s.w};
        float h2[4] = {a.x * s.x, a.y * s.y, a.z * s.z, a.w * s.w};
#pragma unroll
        for (int u = 0; u < 4; u++) {
            int k = k4 * 4 + u;
#pragma unroll
            for (int j = 0; j < DOUT; j++) {
                acc1[j] += h1[u] * sW1[k * DOUT + j];
                acc2[j] += h2[u] * sW2[k * DOUT + j];
            }
        }
    }
    float y[DOUT], nrm = 0.f;
#pragma unroll
    for (int j = 0; j < DOUT; j++) {
        float v = leaky(acc1[j]) + leaky(acc2[j]);
        y[j] = v;
        nrm += v * v;
    }
    float inv = 1.0f / fmaxf(sqrtf(nrm), 1e-12f);
    float* o = out + (size_t)i * 112 + out_col0;
#pragma unroll
    for (int j = 0; j < DOUT; j++) {
        if (xnext) xnext[(size_t)i * DOUT + j] = y[j];
        o[j] = y[j] * inv;
    }
}

extern "C" void kernel_launch(void* const* d_in, const int* in_sizes, int n_in,
                              void* d_out, int out_size, void* d_ws, size_t ws_size,
                              hipStream_t stream) {
    const float* Eemb = (const float*)d_in[0];
    const float* ev   = (const float*)d_in[1];
    const int*   rows = (const int*)d_in[2];
    const int*   cols = (const int*)d_in[3];
    const float* W1_0 = (const float*)d_in[4];
    const float* b1_0 = (const float*)d_in[5];
    const float* W2_0 = (const float*)d_in[6];
    const float* b2_0 = (const float*)d_in[7];
    const float* W1_1 = (const float*)d_in[8];
    const float* b1_1 = (const float*)d_in[9];
    const float* W2_1 = (const float*)d_in[10];
    const float* b2_1 = (const float*)d_in[11];
    float* out = (float*)d_out;

    int N  = in_sizes[0] / 64;
    int NE = in_sizes[1];

    size_t pairs_b = (size_t)NE * sizeof(int2);
    size_t cur_b   = (size_t)N * sizeof(int);
    size_t blk_b   = 4096;
    size_t x1_b    = (size_t)N * 32 * sizeof(float);
    size_t need    = pairs_b + cur_b + blk_b + x1_b;

    copy_E_kernel<<<(N * 16 + 255) / 256, 256, 0, stream>>>(Eemb, out, N);

    if (ws_size >= need) {
        int2*  pairs = (int2*)d_ws;
        int*   cur   = (int*)((char*)d_ws + pairs_b);
        int*   blk   = (int*)((char*)d_ws + pairs_b + cur_b);
        float* x1    = (float*)((char*)d_ws + pairs_b + cur_b + blk_b);

        hipMemsetAsync(cur, 0, cur_b, stream);
        hist_kernel<<<(NE + 255) / 256, 256, 0, stream>>>(rows, cur, NE);
        int nb = (N + 1023) / 1024;  // 147 <= 256
        scan1_kernel<<<nb, 1024, 0, stream>>>(cur, blk, N);
        scan2_kernel<<<1, 256, 0, stream>>>(blk, nb);
        scan3_kernel<<<nb, 1024, 0, stream>>>(cur, blk, N);
        scatter_kernel<<<(NE + 255) / 256, 256, 0, stream>>>(rows, cols, ev, cur, pairs, NE);

        pull_layer_kernel<64, 32><<<(N + 15) / 16, 256, 0, stream>>>(
            Eemb, pairs, cur, W1_0, b1_0, W2_0, b2_0, x1, out, 64, N);
        pull_layer_kernel<32, 16><<<(N + 31) / 32, 256, 0, stream>>>(
            x1, pairs, cur, W1_1, b1_1, W2_1, b2_1, nullptr, out, 96, N);
    } else {
        // fallback: round-1 push-atomic path (needs N*96*4 bytes)
        float* side0 = (float*)d_ws;
        float* side1 = side0 + (size_t)N * 64;
        float* x1    = side1 + (size_t)N * 32;
        hipMemsetAsync(d_ws, 0, (size_t)N * 96 * sizeof(float), stream);
        int total0 = NE * 64;
        spmm_kernel<6><<<(total0 + 255) / 256, 256, 0, stream>>>(Eemb, ev, rows, cols, side0, total0);
        layer_kernel<64, 32><<<(N + 255) / 256, 256, 0, stream>>>(
            Eemb, side0, W1_0, b1_0, W2_0, b2_0, x1, out, 64, N);
        int total1 = NE * 32;
        spmm_kernel<5><<<(total1 + 255) / 256, 256, 0, stream>>>(x1, ev, rows, cols, side1, total1);
        layer_kernel<32, 16><<<(N + 255) / 256, 256, 0, stream>>>(
            x1, side1, W1_1, b1_1, W2_1, b2_1, nullptr, out, 96, N);
    }
}